// Round 1
// 223.251 us; speedup vs baseline: 1.0023x; 1.0023x over previous
//
#include <hip/hip_runtime.h>

// LinearKoopmanLayer: out[b,2f,t]   = c*x[b,2f,t] - s*x[b,2f+1,t]
//                     out[b,2f+1,t] = s*x[b,2f,t] + c*x[b,2f+1,t]
// a = amp[f]^dt[b], c = a*cos(freq[f]*dt[b]), s = a*sin(freq[f]*dt[b]).
//
// Pure streaming transform (268 MB traffic, zero reuse) -> HBM-bound.
// This revision raises per-wave memory-level parallelism: each block
// handles CHUNKS=4 consecutive (b,f) row-pairs, issuing all 8x16B
// nontemporal loads per thread BEFORE any dependent math, so 8 VMEM ops
// are in flight per wave (was 2). Grid shrinks 16384 -> 4096 blocks.
// Coefficients use raw AMDGCN transcendentals (v_log/v_exp/v_sin/v_cos;
// revolutions, hence the 1/2pi scale) on wave-uniform values; their
// latency hides under the vmcnt waits.

constexpr int Bn = 256;
constexpr int Fn = 64;
constexpr int Tn = 1024;
constexpr int CHUNKS = 4;              // (b,f) row-pairs per block

typedef float v4f __attribute__((ext_vector_type(4)));

__global__ __launch_bounds__(256) void koopman_kernel(
    const float* __restrict__ x,
    const float* __restrict__ delta_t,
    const float* __restrict__ amplitudes,
    const float* __restrict__ frequencies,
    float* __restrict__ out) {
    const int t   = threadIdx.x;               // 0..255, covers Tn/4 v4f
    const int bf0 = blockIdx.x * CHUNKS;       // first (b,f) pair

    // Each chunk is a contiguous 2048-float (512 v4f) region:
    //   [0,256) v4f = row 2f (x0), [256,512) v4f = row 2f+1 (x1).
    const v4f* __restrict__ xp = reinterpret_cast<const v4f*>(x)
                               + (size_t)bf0 * (2 * Tn / 4);
    v4f*       __restrict__ op = reinterpret_cast<v4f*>(out)
                               + (size_t)bf0 * (2 * Tn / 4);

    // 1) Issue ALL streaming loads first: 8 x 16B in flight per thread.
    v4f v0[CHUNKS], v1[CHUNKS];
#pragma unroll
    for (int j = 0; j < CHUNKS; ++j) {
        v0[j] = __builtin_nontemporal_load(&xp[j * 512 + t]);
        v1[j] = __builtin_nontemporal_load(&xp[j * 512 + 256 + t]);
    }

    // 2) Wave-uniform coefficient math (scalar loads + ~8 VALU / chunk),
    //    overlapped with the outstanding vmcnt by the scheduler.
    float cc[CHUNKS], ss[CHUNKS];
#pragma unroll
    for (int j = 0; j < CHUNKS; ++j) {
        const int bf = bf0 + j;
        const int b  = bf >> 6;                // F = 64
        const int f  = bf & 63;
        const float d = delta_t[b];
        // amp^d = exp2(d * log2(amp)), amp in [0.7,1.3]
        const float a = __builtin_amdgcn_exp2f(d * __builtin_amdgcn_logf(amplitudes[f]));
        // v_sin/v_cos take revolutions: sin(ang) = v_sin(ang / 2pi)
        const float rev = (frequencies[f] * d) * 0.15915494309189535f;
        ss[j] = a * __builtin_amdgcn_sinf(rev);
        cc[j] = a * __builtin_amdgcn_cosf(rev);
    }

    // 3) Rotate + store per chunk; chunk j only needs loads 2j,2j+1 so the
    //    compiler can retire stores under partial vmcnt waits.
#pragma unroll
    for (int j = 0; j < CHUNKS; ++j) {
        const v4f r0 = cc[j] * v0[j] - ss[j] * v1[j];
        const v4f r1 = ss[j] * v0[j] + cc[j] * v1[j];
        __builtin_nontemporal_store(r0, &op[j * 512 + t]);
        __builtin_nontemporal_store(r1, &op[j * 512 + 256 + t]);
    }
}

extern "C" void kernel_launch(void* const* d_in, const int* in_sizes, int n_in,
                              void* d_out, int out_size, void* d_ws, size_t ws_size,
                              hipStream_t stream) {
    const float* x    = (const float*)d_in[0];
    const float* dt   = (const float*)d_in[1];
    const float* amp  = (const float*)d_in[2];
    const float* freq = (const float*)d_in[3];
    float* out = (float*)d_out;

    static_assert((Bn * Fn) % CHUNKS == 0, "grid divisibility");
    koopman_kernel<<<dim3(Bn * Fn / CHUNKS), dim3(256), 0, stream>>>(x, dt, amp, freq, out);
}